// Round 14
// baseline (153.326 us; speedup 1.0000x reference)
//
#include <hip/hip_runtime.h>

typedef float f32x4 __attribute__((ext_vector_type(4)));
typedef unsigned short u16x8 __attribute__((ext_vector_type(8)));
typedef __bf16 bf16x8 __attribute__((ext_vector_type(8)));
typedef __bf16 bf16x4 __attribute__((ext_vector_type(4)));

// ---------------------------------------------------------------------------
// Kernel 1: convert + transpose three W (fp32 [256 k][512 n]) into bf16 W^T
// [role][512 n][256 k] in workspace, via 64x64 LDS tile transpose.
// ---------------------------------------------------------------------------
__global__ __launch_bounds__(256) void convert_w_kernel(
    const float* __restrict__ Wt_, const float* __restrict__ Wi_,
    const float* __restrict__ Wo_, unsigned short* __restrict__ out)
{
    __shared__ unsigned short tile[64][72];

    const int b    = blockIdx.x;
    const int role = b >> 5;
    const int kt   = (b & 31) >> 3;
    const int nt   = b & 7;
    const float* __restrict__ W = (role == 0) ? Wt_ : ((role == 1) ? Wi_ : Wo_);

    const int t  = threadIdx.x;
    const int r0 = t >> 4;
    const int c4 = (t & 15) << 2;

#pragma unroll
    for (int j = 0; j < 4; ++j) {
        const int kl = r0 + j * 16;
        f32x4 v = *(const f32x4*)(W + (size_t)(kt * 64 + kl) * 512 + nt * 64 + c4);
#pragma unroll
        for (int e = 0; e < 4; ++e)
            tile[c4 + e][kl] = __builtin_bit_cast(unsigned short, (__bf16)v[e]);
    }
    __syncthreads();

    const int cs = t & 7;
#pragma unroll
    for (int p = 0; p < 2; ++p) {
        const int r = (t >> 3) + p * 32;
        u16x8 v = *(const u16x8*)&tile[r][cs * 8];
        *(u16x8*)(out + (size_t)role * 512 * 256 +
                  (size_t)(nt * 64 + r) * 256 + kt * 64 + cs * 8) = v;
    }
}

// ---------------------------------------------------------------------------
// Kernel 2: ZERO-BARRIER wave-private streaming GEMM (R10 components, no
// synchronization at all). Wave = 32 exclusive rows x 512 cols. Each wave:
//  (1) stages its own 32x256 fp32 rows -> bf16 XOR-swizzled into its OWN
//      16 KB LDS region (full-density lane-consecutive cached loads),
//  (2) ds_reads its 16 A-fragments into 64 VGPRs (same-wave ordering,
//      compiler-inserted lgkmcnt, no barrier),
//  (3) streams 8 column-quads: 32 W loads (L2-hot) + 64 MFMA + R10's
//      transpose epilogue through the wave's now-dead tile as scratch +
//      8 NT full-line stores (4 rows x 256 B per instruction).
// NT stores are spread across the wave's whole lifetime and 8 waves/CU
// drift freely -> continuous HBM read+write issue (R1-R13 all had
// block-phase lockstep; best R10=113us had one barrier + terminal burst).
// ---------------------------------------------------------------------------
__global__ __launch_bounds__(256, 2) void role_proj_kernel(
    const float* __restrict__ A,            // [131072][256] fp32
    const int* __restrict__ tmask,          // [64]
    const int* __restrict__ imask,          // [64]
    const unsigned short* __restrict__ Wws, // [3][512][256] bf16 (W^T)
    const float* __restrict__ bt, const float* __restrict__ bi,
    const float* __restrict__ bo,
    float* __restrict__ C)                  // [131072][512] fp32
{
    // 4 waves x 16 KB wave-private region (A tile, later reused as scratch)
    __shared__ __align__(16) unsigned char smem[64 * 1024];

    const int tid  = threadIdx.x;
    const int lane = tid & 63;
    const int wid  = tid >> 6;              // 0..3
    const int l15  = lane & 15;
    const int l4   = lane >> 4;             // 0..3
    const int r7   = l15 & 7;

    const int m0w  = blockIdx.x * 128 + wid * 32;   // wave's first row

    // role uniform per block: mask index = row/2048 = blockIdx/16
    const int mi   = blockIdx.x >> 4;
    const int role = tmask[mi] ? 0 : (imask[mi] ? 1 : 2);
    const unsigned short* __restrict__ W = Wws + (size_t)role * (512 * 256);
    const float* __restrict__ bias = (role == 0) ? bt : ((role == 1) ? bi : bo);

    unsigned char* tilep = smem + wid * 16384;

    // ---- Phase 1: stage wave's 32 rows (32 KB fp32), full-density cached
    // loads: instruction = 64 lanes x consecutive 16 B = 1 KB contiguous.
    const f32x4* ab = (const f32x4*)(A + (size_t)m0w * 256);
#pragma unroll
    for (int c = 0; c < 4; ++c) {
        f32x4 ld[8];
#pragma unroll
        for (int j = 0; j < 8; ++j)
            ld[j] = ab[(c * 8 + j) * 64 + lane];       // cached (L3-friendly)
#pragma unroll
        for (int j = 0; j < 8; ++j) {
            const int u    = (c * 8 + j) * 64 + lane;  // 16B-unit index
            const int row  = u >> 6;                   // 64 units per row
            const int slot = ((u & 63) >> 1) ^ (row & 7);
            bf16x4 pk = { (__bf16)ld[j][0], (__bf16)ld[j][1],
                          (__bf16)ld[j][2], (__bf16)ld[j][3] };
            *(bf16x4*)(tilep + row * 512 + slot * 16 + (u & 1) * 8) = pk;
        }
    }

    // ---- Phase 2: fragment reads into registers (same-wave, no barrier).
    bf16x8 abf[2][8];
#pragma unroll
    for (int g = 0; g < 2; ++g)
#pragma unroll
        for (int ks = 0; ks < 8; ++ks) {
            const int row  = g * 16 + l15;
            const int slot = (ks * 4 + l4) ^ r7;
            abf[g][ks] = *(const bf16x8*)(tilep + row * 512 + slot * 16);
        }

    // ---- Phase 3: stream 8 column-quads (64 ch each). Tile region is dead
    // now -> its first 4 KB is this wave's transpose scratch.
    unsigned char* cs = tilep;

#pragma unroll 1
    for (int fq = 0; fq < 8; ++fq) {
        f32x4 acc[2][4] = {};     // [g][f]
#pragma unroll
        for (int f = 0; f < 4; ++f) {
            const unsigned short* wp =
                W + (size_t)((fq * 4 + f) * 16 + l15) * 256 + l4 * 8;
            u16x8 bfr[8];
#pragma unroll
            for (int ks = 0; ks < 8; ++ks)
                bfr[ks] = *(const u16x8*)(wp + ks * 32);   // L2-hot
#pragma unroll
            for (int ks = 0; ks < 8; ++ks) {
                // swapped operands: acc row = out-channel (4 consecutive per
                // lane via reg idx), col = activation row (l15)
                acc[0][f] = __builtin_amdgcn_mfma_f32_16x16x32_bf16(
                    __builtin_bit_cast(bf16x8, bfr[ks]), abf[0][ks],
                    acc[0][f], 0, 0, 0);
                acc[1][f] = __builtin_amdgcn_mfma_f32_16x16x32_bf16(
                    __builtin_bit_cast(bf16x8, bfr[ks]), abf[1][ks],
                    acc[1][f], 0, 0, 0);
            }
        }

        f32x4 bv[4];
#pragma unroll
        for (int f = 0; f < 4; ++f)
            bv[f] = *(const f32x4*)(bias + (fq * 4 + f) * 16 + l4 * 4);

        // ---- R10 epilogue, wave-private: per group g, transpose 16 rows x
        // 64 ch through 4 KB scratch, then NT store 4 rows x 256 B / instr.
#pragma unroll
        for (int g = 0; g < 2; ++g) {
#pragma unroll
            for (int f = 0; f < 4; ++f) {
                const int s = (f * 4 + l4) ^ r7;
                *(f32x4*)(cs + l15 * 256 + s * 16) = acc[g][f] + bv[f];
            }
            asm volatile("s_waitcnt lgkmcnt(0)" ::: "memory");
#pragma unroll
            for (int q = 0; q < 4; ++q) {
                const int r = l4 + 4 * q;              // act-row 0..15
                const int s = l15 ^ (r & 7);           // swizzled 16B unit
                f32x4 v = *(const f32x4*)(cs + r * 256 + s * 16);
                __builtin_nontemporal_store(
                    v, (f32x4*)(C + (size_t)(m0w + g * 16 + r) * 512 +
                                fq * 64 + l15 * 4));
            }
            asm volatile("s_waitcnt lgkmcnt(0)" ::: "memory");
        }
    }
}

extern "C" void kernel_launch(void* const* d_in, const int* in_sizes, int n_in,
                              void* d_out, int out_size, void* d_ws, size_t ws_size,
                              hipStream_t stream) {
    const float* A   = (const float*)d_in[0];
    const int*   tm  = (const int*)d_in[1];
    const int*   im  = (const int*)d_in[2];
    const float* Wt_ = (const float*)d_in[3];
    const float* bt  = (const float*)d_in[4];
    const float* Wi_ = (const float*)d_in[5];
    const float* bi  = (const float*)d_in[6];
    const float* Wo_ = (const float*)d_in[7];
    const float* bo  = (const float*)d_in[8];

    unsigned short* Wws = (unsigned short*)d_ws;   // 3*512*256*2 = 768 KB

    hipLaunchKernelGGL(convert_w_kernel, dim3(96), dim3(256),
                       0, stream, Wt_, Wi_, Wo_, Wws);

    hipLaunchKernelGGL(role_proj_kernel, dim3(1024), dim3(256),
                       0, stream, A, tm, im, Wws, bt, bi, bo, (float*)d_out);
}

// Round 15
// 114.132 us; speedup vs baseline: 1.3434x; 1.3434x over previous
//
#include <hip/hip_runtime.h>

typedef float f32x4 __attribute__((ext_vector_type(4)));
typedef unsigned short u16x8 __attribute__((ext_vector_type(8)));
typedef __bf16 bf16x8 __attribute__((ext_vector_type(8)));
typedef __bf16 bf16x4 __attribute__((ext_vector_type(4)));

// ---------------------------------------------------------------------------
// Kernel 1: convert + transpose three W (fp32 [256 k][512 n]) into bf16 W^T
// [role][512 n][256 k] in workspace, via 64x64 LDS tile transpose.
// ---------------------------------------------------------------------------
__global__ __launch_bounds__(256) void convert_w_kernel(
    const float* __restrict__ Wt_, const float* __restrict__ Wi_,
    const float* __restrict__ Wo_, unsigned short* __restrict__ out)
{
    __shared__ unsigned short tile[64][72];

    const int b    = blockIdx.x;
    const int role = b >> 5;
    const int kt   = (b & 31) >> 3;
    const int nt   = b & 7;
    const float* __restrict__ W = (role == 0) ? Wt_ : ((role == 1) ? Wi_ : Wo_);

    const int t  = threadIdx.x;
    const int r0 = t >> 4;
    const int c4 = (t & 15) << 2;

#pragma unroll
    for (int j = 0; j < 4; ++j) {
        const int kl = r0 + j * 16;
        f32x4 v = *(const f32x4*)(W + (size_t)(kt * 64 + kl) * 512 + nt * 64 + c4);
#pragma unroll
        for (int e = 0; e < 4; ++e)
            tile[c4 + e][kl] = __builtin_bit_cast(unsigned short, (__bf16)v[e]);
    }
    __syncthreads();

    const int cs = t & 7;
#pragma unroll
    for (int p = 0; p < 2; ++p) {
        const int r = (t >> 3) + p * 32;
        u16x8 v = *(const u16x8*)&tile[r][cs * 8];
        *(u16x8*)(out + (size_t)role * 512 * 256 +
                  (size_t)(nt * 64 + r) * 256 + kt * 64 + cs * 8) = v;
    }
}

// ---------------------------------------------------------------------------
// Kernel 2: EXACT R10 champion (113 us) with ONE structural change: the
// epilogue scratch REUSES the dead A-tile (LDS 64 KB -> 32 KB), doubling
// co-resident blocks per CU from 2 to 4. Cost: one extra raw s_barrier
// (lgkmcnt-only; no VMEM drain -- A loads retired at staging, NT stores not
// yet issued) so all waves finish reading As before it's overwritten.
// 4 staggered block-phases/CU let one block's NT store burst overlap
// another's stage/compute (R14 proved traffic volume is ideal at 342 MB;
// the residual is HBM duty cycle between big bursts).
// ---------------------------------------------------------------------------
__global__ __launch_bounds__(512, 4) void role_proj_kernel(
    const float* __restrict__ A,            // [131072][256] fp32
    const int* __restrict__ tmask,          // [64]
    const int* __restrict__ imask,          // [64]
    const unsigned short* __restrict__ Wws, // [3][512][256] bf16 (W^T)
    const float* __restrict__ bt, const float* __restrict__ bi,
    const float* __restrict__ bo,
    float* __restrict__ C)                  // [131072][512] fp32
{
    // 32 KB: bf16 A tile (staging/compute), reused as epilogue scratch.
    __shared__ __align__(16) unsigned char smem[32 * 1024];
    unsigned short* As = (unsigned short*)smem;

    const int tid = threadIdx.x;
    const int m0  = blockIdx.x * 64;

    // role uniform per block: mask index = t/32 = blockIdx/32
    const int mi   = blockIdx.x >> 5;
    const int role = tmask[mi] ? 0 : (imask[mi] ? 1 : 2);
    const unsigned short* __restrict__ W = Wws + (size_t)role * (512 * 256);
    const float* __restrict__ bias = (role == 0) ? bt : ((role == 1) ? bi : bo);

    // ---- Phase 1: stage A (64 x 256 fp32 = 64 KB), full-density CACHED
    // loads (L3-resident across replays). Instruction p: 64 lanes x
    // consecutive 16 B = 1 KB contiguous.
    const f32x4* abase = (const f32x4*)(A + (size_t)m0 * 256);
    f32x4 ld[8];
#pragma unroll
    for (int p = 0; p < 8; ++p)
        ld[p] = abase[tid + 512 * p];
#pragma unroll
    for (int p = 0; p < 8; ++p) {
        const int u    = tid + 512 * p;       // float4-unit index in tile
        const int row  = u >> 6;              // 64 units per 256-float row
        const int slot = ((u & 63) >> 1) ^ (row & 7);   // 16 B slot, swizzled
        bf16x4 pk = { (__bf16)ld[p][0], (__bf16)ld[p][1],
                      (__bf16)ld[p][2], (__bf16)ld[p][3] };
        *(bf16x4*)(smem + row * 512 + slot * 16 + (u & 1) * 8) = pk;
    }
    __syncthreads();   // staging barrier (no outstanding stores)

    // ---- Phase 2: compute. Wave = 64 rows x 64 cols (wid strip).
    const int lane  = tid & 63;
    const int wid   = tid >> 6;
    const int l15   = lane & 15;
    const int l4    = lane >> 4;
    const int nbase = wid * 64;
    const int r7    = l15 & 7;

    const unsigned short* wp[4];
#pragma unroll
    for (int fn = 0; fn < 4; ++fn)
        wp[fn] = W + (size_t)(nbase + fn * 16 + l15) * 256 + l4 * 8;

    f32x4 acc[4][4] = {};          // [fm][fn]

#pragma unroll 1
    for (int ks = 0; ks < 8; ++ks) {
        u16x8 bfr[4];
#pragma unroll
        for (int fn = 0; fn < 4; ++fn)
            bfr[fn] = *(const u16x8*)(wp[fn] + ks * 32);   // L1/L2-resident
        u16x8 afr[4];
#pragma unroll
        for (int fm = 0; fm < 4; ++fm) {
            const int row  = fm * 16 + l15;
            const int slot = (ks * 4 + l4) ^ r7;
            afr[fm] = *(const u16x8*)&As[row * 256 + slot * 8];
        }
#pragma unroll
        for (int fm = 0; fm < 4; ++fm) {
#pragma unroll
            for (int fn = 0; fn < 4; ++fn) {
                // swapped operands: acc row = out-channel (4 consecutive per
                // lane via reg idx), col = activation row
                acc[fm][fn] = __builtin_amdgcn_mfma_f32_16x16x32_bf16(
                    __builtin_bit_cast(bf16x8, bfr[fn]),
                    __builtin_bit_cast(bf16x8, afr[fm]),
                    acc[fm][fn], 0, 0, 0);
            }
        }
    }

    // all waves done reading As; safe to reuse as scratch. Raw barrier:
    // lgkmcnt(0) only -- no VMEM drain (loads retired, stores not issued).
    __builtin_amdgcn_sched_barrier(0);
    asm volatile("s_waitcnt lgkmcnt(0)\n\ts_barrier" ::: "memory");
    __builtin_amdgcn_sched_barrier(0);

    // ---- Phase 3: wave-private epilogue in the dead A-tile, NO barriers.
    // Scratch: this wave's 4 KB = [16 act-rows][64 ch] fp32, 16 B-unit XOR
    // swizzle. Same-wave ds ordering guaranteed by data deps.
    unsigned char* cs = smem + wid * 4096;

    f32x4 bv[4];
#pragma unroll
    for (int fn = 0; fn < 4; ++fn)
        bv[fn] = *(const f32x4*)(bias + nbase + fn * 16 + l4 * 4);

#pragma unroll
    for (int fm = 0; fm < 4; ++fm) {
        // write acc slice: row = l15, 16B-unit g = fn*4+l4, swizzled by row
#pragma unroll
        for (int fn = 0; fn < 4; ++fn) {
            const int g = (fn * 4 + l4) ^ r7;
            *(f32x4*)(cs + l15 * 256 + g * 16) = acc[fm][fn] + bv[fn];
        }
        // read lane-linear + NT store: 4 rows x 256 B contiguous per instr
#pragma unroll
        for (int q = 0; q < 4; ++q) {
            const int r = (lane >> 4) + 4 * q;           // act-row 0..15
            const int g = (lane & 15) ^ (r & 7);         // swizzled 16B unit
            f32x4 v = *(const f32x4*)(cs + r * 256 + g * 16);
            __builtin_nontemporal_store(
                v, (f32x4*)(C + (size_t)(m0 + fm * 16 + r) * 512 +
                            nbase + (lane & 15) * 4));
        }
    }
}

extern "C" void kernel_launch(void* const* d_in, const int* in_sizes, int n_in,
                              void* d_out, int out_size, void* d_ws, size_t ws_size,
                              hipStream_t stream) {
    const float* A   = (const float*)d_in[0];
    const int*   tm  = (const int*)d_in[1];
    const int*   im  = (const int*)d_in[2];
    const float* Wt_ = (const float*)d_in[3];
    const float* bt  = (const float*)d_in[4];
    const float* Wi_ = (const float*)d_in[5];
    const float* bi  = (const float*)d_in[6];
    const float* Wo_ = (const float*)d_in[7];
    const float* bo  = (const float*)d_in[8];

    unsigned short* Wws = (unsigned short*)d_ws;   // 3*512*256*2 = 768 KB

    hipLaunchKernelGGL(convert_w_kernel, dim3(96), dim3(256),
                       0, stream, Wt_, Wi_, Wo_, Wws);

    hipLaunchKernelGGL(role_proj_kernel, dim3(2048), dim3(512),
                       0, stream, A, tm, im, Wws, bt, bi, bo, (float*)d_out);
}